// Round 16
// baseline (16757.443 us; speedup 1.0000x reference)
//
#include <hip/hip_runtime.h>
#include <math.h>

// KMeansGrouping: B=32, N=4096, D=256, K=24, 25 iters.
// Round 16: r8's exact pipeline (best known, 1729us) with dispatch-count
// surgery, zero numerical change:
//  (a) k_upd2 fused into k_cluster4 via last-block-done: the 4 quarter-blocks
//      of each (b,k) ATOM_ST psums (agent scope -- r10-proven cross-XCD
//      primitive), threadfence, fetch_add an arrival counter; the 4th arrival
//      combines in the SAME fixed order -> bit-identical result regardless of
//      arrival order, then resets the counter. centers/cT32/c_sq are plain
//      stores read only by the NEXT dispatch (boundary release/acquire, same
//      mechanism r8 already relies on).
//  (b) final assign writes masks directly (r15-verified FINAL template).
// 77 -> 55 dispatches; -125us upd2 + ~75us gaps.

#define BATCH 32
#define NPTS 4096
#define DIM 256
#define NSLOT 24
#define NITER 25
#define QPTS 1024 // points per k_cluster4 block

#define ATOM_ST(p, v) __hip_atomic_store((p), (v), __ATOMIC_RELAXED, __HIP_MEMORY_SCOPE_AGENT)
#define ATOM_LD(p) __hip_atomic_load((p), __ATOMIC_RELAXED, __HIP_MEMORY_SCOPE_AGENT)

// ---------------- K0: per-point inverse norm (f64) ----------------
__global__ __launch_bounds__(256) void k_norm(const float* __restrict__ feat,
                                              double* __restrict__ inv_norm) {
  int lane = threadIdx.x & 63;
  int wid = threadIdx.x >> 6;
  int p = blockIdx.x * 4 + wid; // one wave per point
  const float4 v = *(const float4*)(feat + (size_t)p * DIM + lane * 4);
  double s = (double)v.x * v.x + (double)v.y * v.y + (double)v.z * v.z + (double)v.w * v.w;
#pragma unroll
  for (int m = 32; m; m >>= 1) s += __shfl_xor(s, m);
  if (lane == 0) inv_norm[p] = 1.0 / fmax(sqrt(s), 1e-12);
}

__device__ __forceinline__ double block_sum_256(double v, double* red) {
#pragma unroll
  for (int m = 32; m; m >>= 1) v += __shfl_xor(v, m);
  int w = threadIdx.x >> 6;
  if ((threadIdx.x & 63) == 0) red[w] = v;
  __syncthreads();
  return red[0] + red[1] + red[2] + red[3];
}

// ---------------- K0b: initial centers + zero arrival counters ----------
// init_idx = floor(linspace(0, N-1, K)): idx_k = floor(k*4095/23).
__global__ __launch_bounds__(256) void k_init_centers(const float* __restrict__ feat,
                                                      const double* __restrict__ inv_norm,
                                                      double* __restrict__ centers,
                                                      float* __restrict__ cT32,
                                                      float* __restrict__ c_sq32,
                                                      int* __restrict__ arrive) {
  __shared__ double red[4];
  int t = threadIdx.x, k = blockIdx.x, b = blockIdx.y;
  int idx = (int)((double)k * (NPTS - 1) / (NSLOT - 1));
  double v = (double)feat[((size_t)b * NPTS + idx) * DIM + t] * inv_norm[b * NPTS + idx];
  centers[((size_t)b * NSLOT + k) * DIM + t] = v;
  cT32[((size_t)b * DIM + t) * NSLOT + k] = (float)v;
  double s = block_sum_256(v * v, red);
  if (t == 0) {
    c_sq32[b * NSLOT + k] = (float)s;
    arrive[b * NSLOT + k] = 0;
  }
}

// ---------------- K0c: tiled transpose feat -> xT[b][d][n] (f32) ----------
__global__ __launch_bounds__(256) void k_transpose(const float* __restrict__ feat,
                                                   float* __restrict__ xT) {
  __shared__ float tile[64][65];
  int ix = threadIdx.x & 63, iy = threadIdx.x >> 6;
  int bx = blockIdx.x, by = blockIdx.y, b = blockIdx.z;
  const float* fb = feat + ((size_t)b * NPTS + bx * 64) * DIM + by * 64;
#pragma unroll
  for (int r = 0; r < 64; r += 4)
    tile[r + iy][ix] = fb[(size_t)(r + iy) * DIM + ix];
  __syncthreads();
  float* xb = xT + ((size_t)b * DIM + by * 64) * NPTS + bx * 64;
#pragma unroll
  for (int r = 0; r < 64; r += 4)
    xb[(size_t)(r + iy) * NPTS + ix] = tile[ix][r + iy];
}

// ---------------- K1: assignment (f32 scoring), quarter-D per wave --------
// r8's exact kernel (bit-exact scores). FINAL writes masks directly.
template <bool USE_T, bool FINAL>
__global__ __launch_bounds__(256) void k_assign(const float* __restrict__ feat,
                                                const float* __restrict__ xT,
                                                const double* __restrict__ inv_norm,
                                                const float* __restrict__ cT32,
                                                const float* __restrict__ c_sq32,
                                                int* __restrict__ assign,
                                                float* __restrict__ masks) {
  __shared__ float part[3][64][NSLOT + 1]; // 19200 B, odd lane stride
  int lane = threadIdx.x & 63;
  int q = __builtin_amdgcn_readfirstlane(threadIdx.x >> 6);
  int blk = blockIdx.x, b = blockIdx.y;
  int n = blk * 64 + lane;
  const float* cb = cT32 + ((size_t)b * DIM + q * 64) * NSLOT;

  float dot[NSLOT];
#pragma unroll
  for (int k = 0; k < NSLOT; ++k) dot[k] = 0.0f;

  for (int d = 0; d < 64; d += 8) {
    float x[8];
    if (USE_T) {
      const float* xp = xT + ((size_t)b * DIM + q * 64 + d) * NPTS + n;
#pragma unroll
      for (int j = 0; j < 8; ++j) x[j] = xp[(size_t)j * NPTS];
    } else {
      float4 v = *(const float4*)(feat + ((size_t)b * NPTS + n) * DIM + q * 64 + d);
      float4 u = *(const float4*)(feat + ((size_t)b * NPTS + n) * DIM + q * 64 + d + 4);
      x[0] = v.x; x[1] = v.y; x[2] = v.z; x[3] = v.w;
      x[4] = u.x; x[5] = u.y; x[6] = u.z; x[7] = u.w;
    }
    const float* cp = cb + (size_t)d * NSLOT; // wave-uniform -> s_load
#pragma unroll
    for (int k = 0; k < NSLOT; ++k) {
      float s = dot[k];
#pragma unroll
      for (int j = 0; j < 8; ++j) s = fmaf(x[j], cp[j * NSLOT + k], s);
      dot[k] = s;
    }
  }

  if (q) {
#pragma unroll
    for (int k = 0; k < NSLOT; ++k) part[q - 1][lane][k] = dot[k];
  }
  __syncthreads();

  if (q == 0) {
    float inv = (float)inv_norm[b * NPTS + n];
    const float* csq = c_sq32 + b * NSLOT; // uniform -> s_load
    int a = 0;
    float best = 0.0f;
#pragma unroll
    for (int k = 0; k < NSLOT; ++k) {
      float df = dot[k] + part[0][lane][k] + part[1][lane][k] + part[2][lane][k];
      float s = csq[k] - 2.0f * (df * inv);
      if (k == 0) { best = s; }
      else if (s < best) { best = s; a = k; }
    }
    if (FINAL) {
#pragma unroll
      for (int k = 0; k < NSLOT; ++k)
        masks[((size_t)b * NSLOT + k) * NPTS + n] = (a == k) ? 1.0f : 0.0f;
    } else {
      assign[b * NPTS + n] = a;
    }
  }
}

// ---------------- K2: cluster partial sums + fused last-block combine -----
__global__ __launch_bounds__(256) void k_cluster4F(const float* __restrict__ feat,
                                                   const double* __restrict__ inv_norm,
                                                   const int* __restrict__ assign,
                                                   double* __restrict__ psumG,
                                                   int* __restrict__ cntG,
                                                   int* __restrict__ arrive,
                                                   double* __restrict__ centers,
                                                   float* __restrict__ cT32,
                                                   float* __restrict__ c_sq32) {
  __shared__ unsigned short list[QPTS]; // 2 KB
  __shared__ int wtot[4];
  __shared__ double part[4][DIM];       // 8 KB
  __shared__ double red[4];
  __shared__ int isLast;

  int id = blockIdx.x; // ((b*NSLOT)+k)*4+q
  int q = id & 3;
  int slot = id >> 2;  // b*NSLOT + k
  int k = slot % NSLOT;
  int b = slot / NSLOT;

  int t = threadIdx.x;
  int lane = t & 63;
  int w = __builtin_amdgcn_readfirstlane(t >> 6);

  // ---- phase 1: compaction of this quarter's members (ascending n) ----
  const int* ab = assign + b * NPTS + q * QPTS;
  int base = 0; // block-uniform
  for (int rr = 0; rr < QPTS / 256; ++rr) {
    bool m = (ab[rr * 256 + t] == k);
    unsigned long long bal = __ballot(m);
    int rank = __popcll(bal & ((1ull << lane) - 1ull));
    if (lane == 0) wtot[w] = __popcll(bal);
    __syncthreads();
    int off = base;
#pragma unroll
    for (int w2 = 0; w2 < 3; ++w2)
      if (w2 < w) off += wtot[w2];
    if (m) list[off + rank] = (unsigned short)(rr * 256 + t);
    base += wtot[0] + wtot[1] + wtot[2] + wtot[3];
    __syncthreads();
  }
  int mcount = base;

  // ---- phase 2: striped, 4 rows in flight per wave ----
  const float* fb = feat + ((size_t)b * NPTS + q * QPTS) * DIM + lane * 4;
  const double* ib = inv_norm + b * NPTS + q * QPTS;
  double a0 = 0.0, a1 = 0.0, a2 = 0.0, a3 = 0.0;

  for (int i = w; i < mcount; i += 16) {
    bool h1 = (i + 4) < mcount, h2 = (i + 8) < mcount, h3 = (i + 12) < mcount;
    int n0 = __builtin_amdgcn_readfirstlane((int)list[i]);
    int n1 = __builtin_amdgcn_readfirstlane((int)list[h1 ? i + 4 : i]);
    int n2 = __builtin_amdgcn_readfirstlane((int)list[h2 ? i + 8 : i]);
    int n3 = __builtin_amdgcn_readfirstlane((int)list[h3 ? i + 12 : i]);
    float4 v0 = *(const float4*)(fb + (size_t)n0 * DIM);
    float4 v1 = *(const float4*)(fb + (size_t)n1 * DIM);
    float4 v2 = *(const float4*)(fb + (size_t)n2 * DIM);
    float4 v3 = *(const float4*)(fb + (size_t)n3 * DIM);
    double i0 = ib[n0], i1 = ib[n1], i2 = ib[n2], i3 = ib[n3];
    a0 += (double)v0.x * i0; a1 += (double)v0.y * i0;
    a2 += (double)v0.z * i0; a3 += (double)v0.w * i0;
    if (h1) { a0 += (double)v1.x * i1; a1 += (double)v1.y * i1;
              a2 += (double)v1.z * i1; a3 += (double)v1.w * i1; }
    if (h2) { a0 += (double)v2.x * i2; a1 += (double)v2.y * i2;
              a2 += (double)v2.z * i2; a3 += (double)v2.w * i2; }
    if (h3) { a0 += (double)v3.x * i3; a1 += (double)v3.y * i3;
              a2 += (double)v3.z * i3; a3 += (double)v3.w * i3; }
  }

  part[w][lane * 4 + 0] = a0;
  part[w][lane * 4 + 1] = a1;
  part[w][lane * 4 + 2] = a2;
  part[w][lane * 4 + 3] = a3;
  __syncthreads();

  double s = ((part[0][t] + part[1][t]) + part[2][t]) + part[3][t]; // fixed order
  ATOM_ST(&psumG[(size_t)id * DIM + t], s);
  if (t == 0) ATOM_ST(&cntG[id], mcount);
  __syncthreads();
  __threadfence();
  if (t == 0) {
    int old = __hip_atomic_fetch_add(&arrive[slot], 1, __ATOMIC_ACQ_REL,
                                     __HIP_MEMORY_SCOPE_AGENT);
    isLast = (old == 3);
  }
  __syncthreads();
  if (!isLast) return;

  // ---- fused combine (4th-arriving block; fixed order -> deterministic) ----
  __threadfence();
  int base4 = slot * 4;
  const double* pp = psumG + (size_t)base4 * DIM;
  double s4 = ((ATOM_LD(&pp[t]) + ATOM_LD(&pp[DIM + t])) + ATOM_LD(&pp[2 * DIM + t])) +
              ATOM_LD(&pp[3 * DIM + t]);
  int cnt = ATOM_LD(&cntG[base4]) + ATOM_LD(&cntG[base4 + 1]) +
            ATOM_LD(&cntG[base4 + 2]) + ATOM_LD(&cntG[base4 + 3]);

  size_t ci = (size_t)slot * DIM + t;
  double nc = (cnt > 0) ? (s4 / (double)cnt) : centers[ci];
  centers[ci] = nc; // read next dispatch -> boundary handles visibility
  cT32[((size_t)b * DIM + t) * NSLOT + k] = (float)nc;
  double sq = block_sum_256(nc * nc, red);
  if (t == 0) {
    c_sq32[slot] = (float)sq;
    ATOM_ST(&arrive[slot], 0); // reset for next iteration
  }
}

// ---------------- K3: centers output ----------------
__global__ __launch_bounds__(256) void k_copyc(const double* __restrict__ centers,
                                               float* __restrict__ out_centers) {
  int t = threadIdx.x, k = blockIdx.x, b = blockIdx.y;
  size_t i = ((size_t)b * NSLOT + k) * DIM + t;
  out_centers[i] = (float)centers[i];
}

extern "C" void kernel_launch(void* const* d_in, const int* in_sizes, int n_in,
                              void* d_out, int out_size, void* d_ws, size_t ws_size,
                              hipStream_t stream) {
  (void)in_sizes; (void)n_in; (void)out_size;
  const float* feat = (const float*)d_in[0];
  float* out_centers = (float*)d_out;                           // (32,24,256)
  float* out_masks = out_centers + (size_t)BATCH * NSLOT * DIM; // (32,24,4096)

  // workspace: ~10.2 MB fixed + 134 MB xT tail (optional).
  char* p = (char*)d_ws;
  double* inv_norm = (double*)p; p += (size_t)BATCH * NPTS * 8;            // 1.05 MB
  double* centers  = (double*)p; p += (size_t)BATCH * NSLOT * DIM * 8;     // 1.57 MB
  float* cT32      = (float*)p;  p += (size_t)BATCH * DIM * NSLOT * 4;     // 0.79 MB
  float* c_sq32    = (float*)p;  p += (size_t)BATCH * NSLOT * 4;           // 3 KB
  int* assign      = (int*)p;    p += (size_t)BATCH * NPTS * 4;            // 0.52 MB
  double* psumG    = (double*)p; p += (size_t)BATCH * NSLOT * 4 * DIM * 8; // 6.3 MB
  int* cntG        = (int*)p;    p += (size_t)BATCH * NSLOT * 4 * 4;       // 12 KB
  int* arrive      = (int*)p;    p += (size_t)BATCH * NSLOT * 4;           // 3 KB
  float* xT        = (float*)p;
  size_t need_xT = (size_t)(p - (char*)d_ws) + (size_t)BATCH * DIM * NPTS * 4; // ~144 MB
  bool useT = ws_size >= need_xT;

  k_norm<<<BATCH * NPTS / 4, 256, 0, stream>>>(feat, inv_norm);
  k_init_centers<<<dim3(NSLOT, BATCH), 256, 0, stream>>>(feat, inv_norm, centers,
                                                         cT32, c_sq32, arrive);
  if (useT)
    k_transpose<<<dim3(NPTS / 64, DIM / 64, BATCH), 256, 0, stream>>>(feat, xT);

  dim3 ag(NPTS / 64, BATCH);
  for (int it = 0; it < NITER; ++it) {
    if (useT)
      k_assign<true, false><<<ag, 256, 0, stream>>>(feat, xT, inv_norm, cT32,
                                                    c_sq32, assign, out_masks);
    else
      k_assign<false, false><<<ag, 256, 0, stream>>>(feat, xT, inv_norm, cT32,
                                                     c_sq32, assign, out_masks);
    k_cluster4F<<<NSLOT * BATCH * 4, 256, 0, stream>>>(feat, inv_norm, assign,
                                                       psumG, cntG, arrive,
                                                       centers, cT32, c_sq32);
  }
  if (useT)
    k_assign<true, true><<<ag, 256, 0, stream>>>(feat, xT, inv_norm, cT32,
                                                 c_sq32, assign, out_masks);
  else
    k_assign<false, true><<<ag, 256, 0, stream>>>(feat, xT, inv_norm, cT32,
                                                  c_sq32, assign, out_masks);
  k_copyc<<<dim3(NSLOT, BATCH), 256, 0, stream>>>(centers, out_centers);
}